// Round 8
// baseline (2299.548 us; speedup 1.0000x reference)
//
#include <hip/hip_runtime.h>
#include <hip/hip_fp16.h>

#define Sn 128
#define Bn 64
#define Hn 512
#define Vn 100
#define TSn 31   // T-1 steps

typedef unsigned int   u32;
typedef unsigned short u16;
typedef _Float16 f16x2 __attribute__((ext_vector_type(2)));

// ---- ws byte offsets (~12.8 MB) ----
#define OFF_ENC2  0ull           // fp16 [64][128][512]   8,388,608
#define OFF_WC2T  8388608ull     // u32 [256][512]          524,288  (ctx half of Wcomb, transposed k-pair major)
#define OFF_WIHT  8912896ull     // u32 [3][256][512]     1,572,864
#define OFF_WHHT  10485760ull    // u32 [3][256][512]     1,572,864
#define OFF_WOUTT 12058624ull    // u32 [256][128]          131,072
#define OFF_EMB2  12189696ull    // f32 [100][512]          204,800  (Wcomb_emb @ Wemb^T)
#define OFF_HEXF  12394496ull    // f32 [2][64][512]        262,144  (h exchange, dbuf by t-parity)
#define OFF_HEXH  12656640ull    // u32 [2][64][256]        131,072  (h fp16-pair exchange)
#define OFF_CNT   12787712ull    // u32 [64][16]              4,096  (64B-padded counters)

__device__ __forceinline__ u16 f2h(float f){ _Float16 h=(_Float16)f; return __builtin_bit_cast(u16,h); }
__device__ __forceinline__ f16x2 uh2(u32 u){ return __builtin_bit_cast(f16x2,u); }
__device__ __forceinline__ float2 h2f(u32 u){ f16x2 h=uh2(u); return make_float2((float)h.x,(float)h.y); }
__device__ __forceinline__ u32 pack2h(float a, float b){ return (u32)f2h(a) | ((u32)f2h(b) << 16); }

#if __has_builtin(__builtin_amdgcn_fdot2)
__device__ __forceinline__ float dot2acc(u32 a, u32 b, float acc){
    return __builtin_amdgcn_fdot2(uh2(a), uh2(b), acc, false);
}
#else
__device__ __forceinline__ float dot2acc(u32 a, u32 b, float acc){
    float2 x=h2f(a), y=h2f(b); return acc + x.x*y.x + x.y*y.y;
}
#endif

__device__ __forceinline__ float fast_tanh(float x){
    float e = __expf(2.0f*x);
    return 1.0f - 2.0f/(e + 1.0f);
}
__device__ __forceinline__ float fast_sigmoid(float x){ return 1.0f/(1.0f + __expf(-x)); }

__device__ __forceinline__ float wave_sum(float v){
#pragma unroll
    for (int o = 32; o; o >>= 1) v += __shfl_xor(v, o);
    return v;
}
__device__ __forceinline__ float wave_max(float v){
#pragma unroll
    for (int o = 32; o; o >>= 1) v = fmaxf(v, __shfl_xor(v, o));
    return v;
}

// ---- 4-sibling barrier (round-4 proven mechanism, verbatim) ----
__device__ __forceinline__ void sib_arrive(u32* cnt){
    asm volatile("s_waitcnt vmcnt(0)" ::: "memory");   // drain this wave's volatile stores
    __syncthreads();                                   // all waves drained
    if (threadIdx.x == 0)
        __hip_atomic_fetch_add(cnt, 1u, __ATOMIC_RELAXED, __HIP_MEMORY_SCOPE_AGENT);
}
__device__ __forceinline__ void sib_wait(u32* cnt, u32 target){
    if (threadIdx.x == 0) {
        u32 v;
        do { __builtin_amdgcn_s_sleep(2);
             v = __hip_atomic_load(cnt, __ATOMIC_RELAXED, __HIP_MEMORY_SCOPE_AGENT);
        } while (v < target);
    }
    __syncthreads();
}

// ---------------- prep 1: enc transpose->fp16, transposed fp16 weights, zero counters ----------------
__global__ __launch_bounds__(256) void prep_conv(
    const float* __restrict__ enc, const float* __restrict__ Wcomb,
    const float* __restrict__ Wih, const float* __restrict__ Whh,
    const float* __restrict__ Wout, char* __restrict__ ws)
{
    const int t0 = blockIdx.x*256 + threadIdx.x;
    const int stride = gridDim.x*256;

    // enc [S][B][H] f32 -> [B][S][H] fp16
    {
        u16* de = (u16*)(ws + OFF_ENC2);
        for (int c = t0; c < Sn*Bn*Hn/4; c += stride) {
            const int h4 = c & 127;
            const int s  = (c >> 7) & 127;
            const int bb = c >> 14;
            float4 v = ((const float4*)enc)[(s*Bn + bb)*(Hn/4) + h4];
            ushort4 o;
            o.x = f2h(v.x); o.y = f2h(v.y); o.z = f2h(v.z); o.w = f2h(v.w);
            ((ushort4*)de)[c] = o;
        }
    }
    // WC2T[kp][j] = pack(Wcomb[j][512+2kp], Wcomb[j][512+2kp+1])
    {
        u32* d = (u32*)(ws + OFF_WC2T);
        for (int i = t0; i < 256*512; i += stride) {
            const int j = i & 511, kp = i >> 9;
            const float* s = Wcomb + (size_t)j*2*Hn + 512 + 2*kp;
            d[i] = pack2h(s[0], s[1]);
        }
    }
    // WIHT[g][kp][j] = pack(Wih[g*512+j][2kp], +1)
    {
        u32* d = (u32*)(ws + OFF_WIHT);
        for (int i = t0; i < 3*256*512; i += stride) {
            const int j = i & 511, kp = (i >> 9) & 255, g = i >> 17;
            const float* s = Wih + ((size_t)(g*Hn + j))*Hn + 2*kp;
            d[i] = pack2h(s[0], s[1]);
        }
    }
    // WHHT[g][kp][j]
    {
        u32* d = (u32*)(ws + OFF_WHHT);
        for (int i = t0; i < 3*256*512; i += stride) {
            const int j = i & 511, kp = (i >> 9) & 255, g = i >> 17;
            const float* s = Whh + ((size_t)(g*Hn + j))*Hn + 2*kp;
            d[i] = pack2h(s[0], s[1]);
        }
    }
    // WOUTT[kp][v] (v padded to 128)
    {
        u32* d = (u32*)(ws + OFF_WOUTT);
        for (int i = t0; i < 256*128; i += stride) {
            const int v = i & 127, kp = i >> 7;
            u32 val = 0u;
            if (v < Vn) {
                const float* s = Wout + (size_t)v*Hn + 2*kp;
                val = pack2h(s[0], s[1]);
            }
            d[i] = val;
        }
    }
    u32* cnt = (u32*)(ws + OFF_CNT);
    for (int i = t0; i < 64*16; i += stride) cnt[i] = 0u;
}

// ---------------- prep 2: EMB2[v][j] = sum_k Wcomb[j][k] * Wemb[v][k]  (f32; r7-validated) ----------------
__global__ __launch_bounds__(512) void prep_emb2(
    const float* __restrict__ Wemb, const float* __restrict__ Wcomb,
    char* __restrict__ ws)
{
    float* EMB2 = (float*)(ws + OFF_EMB2);
    const int w = threadIdx.x >> 6;
    const int lane = threadIdx.x & 63;
    const int j = blockIdx.x*8 + w;
    const float4* wc = (const float4*)(Wcomb + (size_t)j*2*Hn);
#pragma unroll
    for (int pass = 0; pass < 2; ++pass) {
        const int v = lane + 64*pass;
        if (v < Vn) {
            const float4* we = (const float4*)(Wemb + (size_t)v*Hn);
            float acc = 0.0f;
            for (int k4 = 0; k4 < 128; ++k4) {
                const float4 a = wc[k4], b = we[k4];
                acc += a.x*b.x + a.y*b.y + a.z*b.z + a.w*b.w;
            }
            EMB2[(size_t)v*Hn + j] = acc;
        }
    }
}

// ---------------- main: 256 blocks x 1024 thr; 4 siblings per b; ONE barrier/step ----------------
// xcd=bid&7, lb=bid>>3, q=xcd&3 (j-quarter), b=2*lb+(xcd>>2)
__global__ __launch_bounds__(1024) void bahdanau_decoder(
    const float* __restrict__ bcomb, const float* __restrict__ bih,
    const float* __restrict__ bhh, const float* __restrict__ bout,
    const float* __restrict__ wvat, const float* __restrict__ bvat,
    const int* __restrict__ tgt, float* __restrict__ out, char* __restrict__ ws)
{
    const u32* WC2T  = (const u32*)(ws + OFF_WC2T);
    const u32* WIHT  = (const u32*)(ws + OFF_WIHT);
    const u32* WHHT  = (const u32*)(ws + OFF_WHHT);
    const u32* WOUTT = (const u32*)(ws + OFF_WOUTT);
    const float* EMB2 = (const float*)(ws + OFF_EMB2);
    float* HEXF = (float*)(ws + OFF_HEXF);
    u32*   HEXH = (u32*)(ws + OFF_HEXH);
    u32*   CNT  = (u32*)(ws + OFF_CNT);

    extern __shared__ __align__(16) u16 enc_lds[];   // [128][512] fp16 = 131072 B
    __shared__ __align__(16) float h_full[Hn];       // fp32 master h
    __shared__ __align__(16) u32   hh32[Hn/2];       // fp16-pair h
    __shared__ __align__(16) u32   ctx32[Hn/2];      // fp16-pair ctx
    __shared__ __align__(16) u16   x16[Hn];          // fp16 x (full)
    __shared__ __align__(16) float scores_s[Sn];
    __shared__ __align__(16) float attnw_s[Sn];
    __shared__ __align__(16) float2 pctx_s[4][256];
    __shared__ __align__(16) float xpart[2][Hn];
    __shared__ __align__(16) float gpart[6][128];
    __shared__ __align__(16) float llog[128];
    __shared__ __align__(16) u16   hn16[128];

    const int tid  = threadIdx.x;
    const int lane = tid & 63;
    const int wid  = tid >> 6;              // 0..15
    const int bid  = blockIdx.x;
    const int xcd  = bid & 7;
    const int lb   = bid >> 3;
    const int q    = xcd & 3;
    const int b    = 2*lb + (xcd >> 2);
    const int j0   = q*128;
    u32* cnt = CNT + b*16;

    // enc slice -> LDS (resident all steps)
    {
        const uint4* src = (const uint4*)(ws + OFF_ENC2 + (size_t)b*Sn*Hn*2);
        for (int i = tid; i < Sn*Hn/8; i += 1024) ((uint4*)enc_lds)[i] = src[i];
    }
    if (tid < Hn)   h_full[tid] = 0.0f;
    if (tid < Hn/2) hh32[tid] = 0u;
    const float4 Wa = ((const float4*)wvat)[2*lane];
    const float4 Wb = ((const float4*)wvat)[2*lane+1];
    const float bv = bvat[0];
    __syncthreads();

    for (int t = 0; t < TSn; ++t) {
        const int buf = t & 1;

        // ---- P1: scores (replicated, r4-proven): wave per s-row ----
        {
            const float4 Ha = ((const float4*)h_full)[2*lane];
            const float4 Hb = ((const float4*)h_full)[2*lane+1];
            for (int s = wid; s < Sn; s += 16) {
                const uint4 E = ((const uint4*)(enc_lds + s*Hn))[lane];
                const float2 e0 = h2f(E.x), e1 = h2f(E.y), e2 = h2f(E.z), e3 = h2f(E.w);
                float acc = fast_tanh(e0.x+Ha.x)*Wa.x + fast_tanh(e0.y+Ha.y)*Wa.y
                          + fast_tanh(e1.x+Ha.z)*Wa.z + fast_tanh(e1.y+Ha.w)*Wa.w
                          + fast_tanh(e2.x+Hb.x)*Wb.x + fast_tanh(e2.y+Hb.y)*Wb.y
                          + fast_tanh(e3.x+Hb.z)*Wb.z + fast_tanh(e3.y+Hb.w)*Wb.w;
                acc = wave_sum(acc);
                if (lane == 0) scores_s[s] = acc + bv;
            }
        }
        // ---- P1b (q=0 only): logits of h_t -> out index t-1 (lane-parallel v, no reduce) ----
        if (q == 0 && t > 0 && wid >= 14) {
            const int v = (wid - 14)*64 + lane;
            if (v < Vn) {
                const u32* wp = WOUTT + v;
                float a0 = 0.f, a1 = 0.f;
#pragma unroll 8
                for (int i4 = 0; i4 < 64; ++i4) {
                    const uint4 hv = ((const uint4*)hh32)[i4];
                    a0 = dot2acc(wp[(4*i4+0)*128], hv.x, a0);
                    a1 = dot2acc(wp[(4*i4+1)*128], hv.y, a1);
                    a0 = dot2acc(wp[(4*i4+2)*128], hv.z, a0);
                    a1 = dot2acc(wp[(4*i4+3)*128], hv.w, a1);
                }
                llog[v] = a0 + a1 + bout[v];
            }
        }
        __syncthreads();

        // ---- P2: softmax over 128 (wave 0) ----
        if (wid == 0) {
            const float s0 = scores_s[lane], s1 = scores_s[lane+64];
            const float mx = wave_max(fmaxf(s0, s1));
            const float e0 = __expf(s0-mx), e1 = __expf(s1-mx);
            const float inv = 1.0f / wave_sum(e0 + e1);
            attnw_s[lane]    = e0 * inv;
            attnw_s[lane+64] = e1 * inv;
        }
        __syncthreads();

        // ---- P3: ctx partials (replicated) ----
        {
            const int op = tid & 255, sc = tid >> 8;
            float ax = 0.0f, ay = 0.0f;
#pragma unroll 8
            for (int i2 = 0; i2 < 32; ++i2) {
                const int s = sc*32 + i2;
                const float a = attnw_s[s];
                const float2 ef = h2f(((const u32*)(enc_lds + s*Hn))[op]);
                ax += a*ef.x; ay += a*ef.y;
            }
            pctx_s[sc][op] = make_float2(ax, ay);
        }
        __syncthreads();
        // ctx combine  ||  (q=0, wave 14): log-softmax + store out[t-1]
        if (tid < 256) {
            const float2 c0 = pctx_s[0][tid], c1 = pctx_s[1][tid];
            const float2 c2 = pctx_s[2][tid], c3 = pctx_s[3][tid];
            ctx32[tid] = pack2h(c0.x+c1.x+c2.x+c3.x, c0.y+c1.y+c2.y+c3.y);
        } else if (q == 0 && t > 0 && wid == 14) {
            const float l0 = llog[lane];
            const float l1 = (lane < 36) ? llog[64+lane] : -3.0e38f;
            const float mx = wave_max(fmaxf(l0, l1));
            const float e0 = __expf(l0 - mx);
            const float e1 = (lane < 36) ? __expf(l1 - mx) : 0.0f;
            const float lse = mx + __logf(wave_sum(e0 + e1));
            float* op2 = out + ((size_t)b*TSn + (t-1))*Vn;
            op2[lane] = l0 - lse;
            if (lane < 36) op2[64 + lane] = l1 - lse;
        }
        __syncthreads();

        // ---- P4: FULL x (lane-parallel j; 16 tasks = 8 j-blocks x 2 k-halves) ----
        {
            const int jb = wid & 7, kh = wid >> 3;
            const int j = jb*64 + lane;
            const u32* wr = WC2T + (size_t)kh*128*512 + j;
            const uint4* cp = ((const uint4*)ctx32) + kh*32;
            float a0 = 0.f, a1 = 0.f;
#pragma unroll 8
            for (int i4 = 0; i4 < 32; ++i4) {
                const uint4 cv = cp[i4];
                a0 = dot2acc(wr[(4*i4+0)*512], cv.x, a0);
                a1 = dot2acc(wr[(4*i4+1)*512], cv.y, a1);
                a0 = dot2acc(wr[(4*i4+2)*512], cv.z, a0);
                a1 = dot2acc(wr[(4*i4+3)*512], cv.w, a1);
            }
            xpart[kh][j] = a0 + a1;
        }
        __syncthreads();
        {
            const int sym = tgt[t*Bn + b];
            if (tid < Hn) {
                const float xv = xpart[0][tid] + xpart[1][tid]
                               + EMB2[(size_t)sym*Hn + tid] + bcomb[tid];
                x16[tid] = f2h(fmaxf(xv, 0.0f));
            }
        }
        __syncthreads();

        // ---- P5: GRU own j-quarter (12 tasks: gate x side x j-half; lane-parallel j) ----
        if (wid < 12) {
            const int g = wid >> 2, side = (wid >> 1) & 1, jh = wid & 1;
            const int jj = jh*64 + lane;
            const u32* wr = (side ? WHHT : WIHT) + (size_t)g*(256*512) + j0 + jj;
            const uint4* op = side ? (const uint4*)hh32 : (const uint4*)x16;
            float a0 = 0.f, a1 = 0.f;
#pragma unroll 8
            for (int i4 = 0; i4 < 64; ++i4) {
                const uint4 ov = op[i4];
                a0 = dot2acc(wr[(4*i4+0)*512], ov.x, a0);
                a1 = dot2acc(wr[(4*i4+1)*512], ov.y, a1);
                a0 = dot2acc(wr[(4*i4+2)*512], ov.z, a0);
                a1 = dot2acc(wr[(4*i4+3)*512], ov.w, a1);
            }
            gpart[g*2 + side][jj] = a0 + a1;
        }
        __syncthreads();
        // gate combine -> h_new own quarter; publish h (volatile, r4 mechanism)
        if (tid < 128) {
            const int jj = tid, j = j0 + jj;
            const float r = fast_sigmoid(gpart[0][jj] + gpart[1][jj] + bih[j] + bhh[j]);
            const float z = fast_sigmoid(gpart[2][jj] + gpart[3][jj] + bih[Hn+j] + bhh[Hn+j]);
            const float n = fast_tanh(gpart[4][jj] + bih[2*Hn+j] + r*(gpart[5][jj] + bhh[2*Hn+j]));
            const float hv = (1.0f - z)*n + z*h_full[j];
            h_full[j] = hv;
            hn16[jj] = f2h(hv);
            ((volatile float*)HEXF)[((size_t)buf*Bn + b)*Hn + j] = hv;
        }
        __syncthreads();
        if (wid == 2) {
            const u32 p = (u32)hn16[2*lane] | ((u32)hn16[2*lane+1] << 16);
            ((volatile u32*)HEXH)[((size_t)buf*Bn + b)*256 + q*64 + lane] = p;
        }
        sib_arrive(cnt);
        sib_wait(cnt, 4u*(t+1));

        // assemble full h_{t+1}
        if (wid < 3) {
            const int qq = (q + 1 + wid) & 3;
            const volatile float* hp = (const volatile float*)HEXF
                                     + ((size_t)buf*Bn + b)*Hn + qq*128;
            h_full[qq*128 + 2*lane]     = hp[2*lane];
            h_full[qq*128 + 2*lane + 1] = hp[2*lane+1];
            hh32[qq*64 + lane] = ((const volatile u32*)HEXH)[((size_t)buf*Bn + b)*256 + qq*64 + lane];
        } else if (wid == 3) {
            hh32[q*64 + lane] = (u32)hn16[2*lane] | ((u32)hn16[2*lane+1] << 16);
        }
        __syncthreads();
    }

    // ---- tail: logits for t = TSn-1 from final h ----
    if (q == 0 && wid >= 14) {
        const int v = (wid - 14)*64 + lane;
        if (v < Vn) {
            const u32* wp = WOUTT + v;
            float a0 = 0.f, a1 = 0.f;
#pragma unroll 8
            for (int i4 = 0; i4 < 64; ++i4) {
                const uint4 hv = ((const uint4*)hh32)[i4];
                a0 = dot2acc(wp[(4*i4+0)*128], hv.x, a0);
                a1 = dot2acc(wp[(4*i4+1)*128], hv.y, a1);
                a0 = dot2acc(wp[(4*i4+2)*128], hv.z, a0);
                a1 = dot2acc(wp[(4*i4+3)*128], hv.w, a1);
            }
            llog[v] = a0 + a1 + bout[v];
        }
    }
    __syncthreads();
    if (q == 0 && wid == 14) {
        const float l0 = llog[lane];
        const float l1 = (lane < 36) ? llog[64+lane] : -3.0e38f;
        const float mx = wave_max(fmaxf(l0, l1));
        const float e0 = __expf(l0 - mx);
        const float e1 = (lane < 36) ? __expf(l1 - mx) : 0.0f;
        const float lse = mx + __logf(wave_sum(e0 + e1));
        float* op2 = out + ((size_t)b*TSn + (TSn-1))*Vn;
        op2[lane] = l0 - lse;
        if (lane < 36) op2[64 + lane] = l1 - lse;
    }
}

extern "C" void kernel_launch(void* const* d_in, const int* in_sizes, int n_in,
                              void* d_out, int out_size, void* d_ws, size_t ws_size,
                              hipStream_t stream) {
    const float* enc   = (const float*)d_in[0];
    const float* Wemb  = (const float*)d_in[1];
    const float* Wcomb = (const float*)d_in[2];
    const float* bcomb = (const float*)d_in[3];
    const float* Wih   = (const float*)d_in[4];
    const float* Whh   = (const float*)d_in[5];
    const float* bih   = (const float*)d_in[6];
    const float* bhh   = (const float*)d_in[7];
    const float* Wout  = (const float*)d_in[8];
    const float* bout  = (const float*)d_in[9];
    const float* wvat  = (const float*)d_in[10];
    const float* bvat  = (const float*)d_in[11];
    const int*   tgt   = (const int*)d_in[12];
    float* out = (float*)d_out;
    char*  ws  = (char*)d_ws;

    prep_conv<<<512, 256, 0, stream>>>(enc, Wcomb, Wih, Whh, Wout, ws);
    prep_emb2<<<64, 512, 0, stream>>>(Wemb, Wcomb, ws);

    void* args[] = { &bcomb, &bih, &bhh, &bout, &wvat, &bvat, &tgt, &out, &ws };
    hipLaunchCooperativeKernel((const void*)bahdanau_decoder,
                               dim3(256), dim3(1024), args, (size_t)(Sn*Hn*2), stream);
}

// Round 9
// 2185.579 us; speedup vs baseline: 1.0521x; 1.0521x over previous
//
#include <hip/hip_runtime.h>
#include <hip/hip_fp16.h>

#define Sn 128
#define Bn 64
#define Hn 512
#define Vn 100
#define TSn 31   // T-1 steps

typedef unsigned int   u32;
typedef unsigned short u16;
typedef _Float16 f16x2 __attribute__((ext_vector_type(2)));

// ---- ws byte offsets (~12.4 MB) ----
#define OFF_ENC2  0ull           // fp16 [64][128][512]  8,388,608  (enc transposed [B][S][H])
#define OFF_WC2   8388608ull     // fp16 [512][512]        524,288  (ctx half of Wcomb, row-major)
#define OFF_WIH   8912896ull     // fp16 [1536][512]     1,572,864
#define OFF_WHH   10485760ull    // fp16 [1536][512]     1,572,864
#define OFF_WOUT  12058624ull    // fp16 [100][512]        102,400
#define OFF_EMB2  12161024ull    // f32  [100][512]        204,800  (Wcomb_emb @ Wemb^T)

__device__ __forceinline__ u16 f2h(float f){ _Float16 h=(_Float16)f; return __builtin_bit_cast(u16,h); }
__device__ __forceinline__ f16x2 uh2(u32 u){ return __builtin_bit_cast(f16x2,u); }
__device__ __forceinline__ float2 h2f(u32 u){ f16x2 h=uh2(u); return make_float2((float)h.x,(float)h.y); }
__device__ __forceinline__ u32 pack2h(float a, float b){ return (u32)f2h(a) | ((u32)f2h(b) << 16); }

#if __has_builtin(__builtin_amdgcn_fdot2)
__device__ __forceinline__ float dot2acc(u32 a, u32 b, float acc){
    return __builtin_amdgcn_fdot2(uh2(a), uh2(b), acc, false);
}
#else
__device__ __forceinline__ float dot2acc(u32 a, u32 b, float acc){
    float2 x=h2f(a), y=h2f(b); return acc + x.x*y.x + x.y*y.y;
}
#endif

__device__ __forceinline__ float dot8h(uint4 w, uint4 v, float acc){
    acc = dot2acc(w.x, v.x, acc); acc = dot2acc(w.y, v.y, acc);
    acc = dot2acc(w.z, v.z, acc); acc = dot2acc(w.w, v.w, acc);
    return acc;
}

__device__ __forceinline__ float fast_tanh(float x){
    float e = __expf(2.0f*x);
    return 1.0f - 2.0f/(e + 1.0f);
}
__device__ __forceinline__ float fast_sigmoid(float x){ return 1.0f/(1.0f + __expf(-x)); }

__device__ __forceinline__ float wave_sum(float v){
#pragma unroll
    for (int o = 32; o; o >>= 1) v += __shfl_xor(v, o);
    return v;
}
__device__ __forceinline__ float wave_max(float v){
#pragma unroll
    for (int o = 32; o; o >>= 1) v = fmaxf(v, __shfl_xor(v, o));
    return v;
}

// ---------------- prep 1: enc transpose -> fp16, row-major fp16 weights ----------------
#define CONV(S,D,N)                                              \
    for (int i = t0; i < (N)/4; i += stride) {                   \
        float4 v = ((const float4*)(S))[i];                      \
        ushort4 o;                                               \
        o.x = f2h(v.x); o.y = f2h(v.y);                          \
        o.z = f2h(v.z); o.w = f2h(v.w);                          \
        ((ushort4*)(D))[i] = o;                                  \
    }

__global__ __launch_bounds__(256) void prep_conv(
    const float* __restrict__ enc, const float* __restrict__ Wcomb,
    const float* __restrict__ Wih, const float* __restrict__ Whh,
    const float* __restrict__ Wout, char* __restrict__ ws)
{
    const int t0 = blockIdx.x*256 + threadIdx.x;
    const int stride = gridDim.x*256;

    // enc [S][B][H] f32 -> [B][S][H] fp16   (validated r7/r8)
    {
        u16* de = (u16*)(ws + OFF_ENC2);
        for (int c = t0; c < Sn*Bn*Hn/4; c += stride) {
            const int h4 = c & 127;
            const int s  = (c >> 7) & 127;
            const int bb = c >> 14;
            float4 v = ((const float4*)enc)[(s*Bn + bb)*(Hn/4) + h4];
            ushort4 o;
            o.x = f2h(v.x); o.y = f2h(v.y); o.z = f2h(v.z); o.w = f2h(v.w);
            ((ushort4*)de)[c] = o;
        }
    }
    // WC2[j][k] = Wcomb[j][512+k]  (row-major fp16; validated r7)
    {
        u16* dc = (u16*)(ws + OFF_WC2);
        for (int i = t0; i < Hn*Hn/4; i += stride) {
            const int j = i >> 7, kk = i & 127;
            float4 v = ((const float4*)Wcomb)[j*256 + 128 + kk];
            ushort4 o;
            o.x = f2h(v.x); o.y = f2h(v.y); o.z = f2h(v.z); o.w = f2h(v.w);
            ((ushort4*)dc)[i] = o;
        }
    }
    CONV(Wih,  (u16*)(ws+OFF_WIH),  3*Hn*Hn)
    CONV(Whh,  (u16*)(ws+OFF_WHH),  3*Hn*Hn)
    CONV(Wout, (u16*)(ws+OFF_WOUT), Vn*Hn)
}

// ---------------- prep 2: EMB2[v][j] = sum_k Wcomb[j][k] * Wemb[v][k]  (validated r7/r8) ----------------
__global__ __launch_bounds__(512) void prep_emb2(
    const float* __restrict__ Wemb, const float* __restrict__ Wcomb,
    char* __restrict__ ws)
{
    float* EMB2 = (float*)(ws + OFF_EMB2);
    const int w = threadIdx.x >> 6;
    const int lane = threadIdx.x & 63;
    const int j = blockIdx.x*8 + w;
    const float4* wc = (const float4*)(Wcomb + (size_t)j*2*Hn);
#pragma unroll
    for (int pass = 0; pass < 2; ++pass) {
        const int v = lane + 64*pass;
        if (v < Vn) {
            const float4* we = (const float4*)(Wemb + (size_t)v*Hn);
            float acc = 0.0f;
            for (int k4 = 0; k4 < 128; ++k4) {
                const float4 a = wc[k4], b = we[k4];
                acc += a.x*b.x + a.y*b.y + a.z*b.z + a.w*b.w;
            }
            EMB2[(size_t)v*Hn + j] = acc;
        }
    }
}

// ---------------- main: 64 blocks x 1024 thr; ONE block per b; ZERO inter-block sync ----------------
__global__ __launch_bounds__(1024) void bahdanau_decoder(
    const float* __restrict__ bcomb, const float* __restrict__ bih,
    const float* __restrict__ bhh, const float* __restrict__ bout,
    const float* __restrict__ wvat, const float* __restrict__ bvat,
    const int* __restrict__ tgt, float* __restrict__ out, const char* __restrict__ ws)
{
    const u16* WC2  = (const u16*)(ws + OFF_WC2);
    const u16* WIH  = (const u16*)(ws + OFF_WIH);
    const u16* WHH  = (const u16*)(ws + OFF_WHH);
    const u16* WOUT = (const u16*)(ws + OFF_WOUT);
    const float* EMB2 = (const float*)(ws + OFF_EMB2);

    extern __shared__ __align__(16) u16 enc_lds[];   // [128][512] fp16 = 131072 B
    __shared__ __align__(16) float h_full[Hn];       // fp32 master h
    __shared__ __align__(16) u32   hh32[Hn/2];       // fp16-pair h
    __shared__ __align__(16) u32   ctx32[Hn/2];      // fp16-pair ctx
    __shared__ __align__(16) u16   x16[Hn];          // fp16 x
    __shared__ __align__(16) float xacc[Hn];         // raw Wc2·ctx
    __shared__ __align__(16) u16   hn16[Hn];         // fp16 h_new
    __shared__ __align__(16) float scores_s[Sn];
    __shared__ __align__(16) float attnw_s[Sn];
    __shared__ __align__(16) float2 pctx_s[4][256];
    __shared__ __align__(16) float llog[128];

    const int tid  = threadIdx.x;
    const int lane = tid & 63;
    const int wid  = tid >> 6;              // 0..15
    const int b    = blockIdx.x;

    // enc slice -> LDS (read once, resident all steps)
    {
        const uint4* src = (const uint4*)(ws + OFF_ENC2 + (size_t)b*Sn*Hn*2);
        for (int i = tid; i < Sn*Hn/8; i += 1024) ((uint4*)enc_lds)[i] = src[i];
    }
    if (tid < Hn)   h_full[tid] = 0.0f;
    if (tid < Hn/2) hh32[tid] = 0u;
    const float4 Wa = ((const float4*)wvat)[2*lane];
    const float4 Wb = ((const float4*)wvat)[2*lane+1];
    const float bv = bvat[0];
    __syncthreads();

    for (int t = 0; t < TSn; ++t) {
        // ---- P1: scores (wave per s-row; r4-proven) ----
        {
            const float4 Ha = ((const float4*)h_full)[2*lane];
            const float4 Hb = ((const float4*)h_full)[2*lane+1];
            for (int s = wid; s < Sn; s += 16) {
                const uint4 E = ((const uint4*)(enc_lds + s*Hn))[lane];
                const float2 e0 = h2f(E.x), e1 = h2f(E.y), e2 = h2f(E.z), e3 = h2f(E.w);
                float acc = fast_tanh(e0.x+Ha.x)*Wa.x + fast_tanh(e0.y+Ha.y)*Wa.y
                          + fast_tanh(e1.x+Ha.z)*Wa.z + fast_tanh(e1.y+Ha.w)*Wa.w
                          + fast_tanh(e2.x+Hb.x)*Wb.x + fast_tanh(e2.y+Hb.y)*Wb.y
                          + fast_tanh(e3.x+Hb.z)*Wb.z + fast_tanh(e3.y+Hb.w)*Wb.w;
                acc = wave_sum(acc);
                if (lane == 0) scores_s[s] = acc + bv;
            }
        }
        __syncthreads();

        // ---- P2: softmax over 128 (wave 0) ----
        if (wid == 0) {
            const float s0 = scores_s[lane], s1 = scores_s[lane+64];
            const float mx = wave_max(fmaxf(s0, s1));
            const float e0 = __expf(s0-mx), e1 = __expf(s1-mx);
            const float inv = 1.0f / wave_sum(e0 + e1);
            attnw_s[lane]    = e0 * inv;
            attnw_s[lane+64] = e1 * inv;
        }
        __syncthreads();

        // ---- P3: ctx partials (thread = (o-pair, s-chunk); r4-proven) ----
        {
            const int op = tid & 255, sc = tid >> 8;
            float ax = 0.0f, ay = 0.0f;
#pragma unroll 8
            for (int i2 = 0; i2 < 32; ++i2) {
                const int s = sc*32 + i2;
                const float a = attnw_s[s];
                const float2 ef = h2f(((const u32*)(enc_lds + s*Hn))[op]);
                ax += a*ef.x; ay += a*ef.y;
            }
            pctx_s[sc][op] = make_float2(ax, ay);
        }
        __syncthreads();
        if (tid < 256) {
            const float2 c0 = pctx_s[0][tid], c1 = pctx_s[1][tid];
            const float2 c2 = pctx_s[2][tid], c3 = pctx_s[3][tid];
            ctx32[tid] = pack2h(c0.x+c1.x+c2.x+c3.x, c0.y+c1.y+c2.y+c3.y);
        }
        __syncthreads();

        // ---- P4: x raw dots (wave per j, full 512 j; uint4 row-dot) ----
        {
            const uint4 C = ((const uint4*)ctx32)[lane];
            for (int j = wid; j < Hn; j += 16) {
                const uint4 W = ((const uint4*)(WC2 + (size_t)j*Hn))[lane];
                float acc = dot8h(W, C, 0.0f);
                acc = wave_sum(acc);
                if (lane == 0) xacc[j] = acc;
            }
        }
        __syncthreads();
        {
            const int sym = tgt[t*Bn + b];
            if (tid < Hn)
                x16[tid] = f2h(fmaxf(xacc[tid] + EMB2[(size_t)sym*Hn + tid] + bcomb[tid], 0.0f));
        }
        __syncthreads();

        // ---- P5: GRU (wave per j, full 512 j; 6 uint4 row-dots, folded reduces) ----
        {
            const uint4 Xv = ((const uint4*)x16)[lane];
            const uint4 Hv = ((const uint4*)hh32)[lane];
            for (int j = wid; j < Hn; j += 16) {
                const uint4 Wr = ((const uint4*)(WIH + (size_t)j*Hn))[lane];
                const uint4 Wz = ((const uint4*)(WIH + (size_t)(Hn + j)*Hn))[lane];
                const uint4 Wn = ((const uint4*)(WIH + (size_t)(2*Hn + j)*Hn))[lane];
                const uint4 Ur = ((const uint4*)(WHH + (size_t)j*Hn))[lane];
                const uint4 Uz = ((const uint4*)(WHH + (size_t)(Hn + j)*Hn))[lane];
                const uint4 Un = ((const uint4*)(WHH + (size_t)(2*Hn + j)*Hn))[lane];
                float gr  = dot8h(Ur, Hv, dot8h(Wr, Xv, 0.0f));
                float gz  = dot8h(Uz, Hv, dot8h(Wz, Xv, 0.0f));
                float gin = dot8h(Wn, Xv, 0.0f);
                float ghn = dot8h(Un, Hv, 0.0f);
                gr = wave_sum(gr); gz = wave_sum(gz);
                gin = wave_sum(gin); ghn = wave_sum(ghn);
                if (lane == 0) {
                    const float r = fast_sigmoid(gr + bih[j] + bhh[j]);
                    const float z = fast_sigmoid(gz + bih[Hn+j] + bhh[Hn+j]);
                    const float n = fast_tanh(gin + bih[2*Hn+j] + r*(ghn + bhh[2*Hn+j]));
                    const float hv = (1.0f - z)*n + z*h_full[j];
                    h_full[j] = hv;
                    hn16[j] = f2h(hv);
                }
            }
        }
        __syncthreads();
        if (tid < Hn/2) hh32[tid] = (u32)hn16[2*tid] | ((u32)hn16[2*tid+1] << 16);
        __syncthreads();

        // ---- P6: logits from h_new (wave per v) ----
        {
            const uint4 Hq = ((const uint4*)hn16)[lane];
            for (int v = wid; v < Vn; v += 16) {
                const uint4 W = ((const uint4*)(WOUT + (size_t)v*Hn))[lane];
                float acc = dot8h(W, Hq, 0.0f);
                acc = wave_sum(acc);
                if (lane == 0) llog[v] = acc + bout[v];
            }
        }
        __syncthreads();

        // ---- P7: log-softmax + store (wave 0) ----
        if (wid == 0) {
            const float l0 = llog[lane];
            const float l1 = (lane < 36) ? llog[64+lane] : -3.0e38f;
            const float mx = wave_max(fmaxf(l0, l1));
            const float e0 = __expf(l0 - mx);
            const float e1 = (lane < 36) ? __expf(l1 - mx) : 0.0f;
            const float lse = mx + __logf(wave_sum(e0 + e1));
            float* op = out + ((size_t)b*TSn + t)*Vn;
            op[lane] = l0 - lse;
            if (lane < 36) op[64 + lane] = l1 - lse;
        }
        __syncthreads();
    }
}

extern "C" void kernel_launch(void* const* d_in, const int* in_sizes, int n_in,
                              void* d_out, int out_size, void* d_ws, size_t ws_size,
                              hipStream_t stream) {
    const float* enc   = (const float*)d_in[0];
    const float* Wemb  = (const float*)d_in[1];
    const float* Wcomb = (const float*)d_in[2];
    const float* bcomb = (const float*)d_in[3];
    const float* Wih   = (const float*)d_in[4];
    const float* Whh   = (const float*)d_in[5];
    const float* bih   = (const float*)d_in[6];
    const float* bhh   = (const float*)d_in[7];
    const float* Wout  = (const float*)d_in[8];
    const float* bout  = (const float*)d_in[9];
    const float* wvat  = (const float*)d_in[10];
    const float* bvat  = (const float*)d_in[11];
    const int*   tgt   = (const int*)d_in[12];
    float* out = (float*)d_out;
    char*  ws  = (char*)d_ws;

    prep_conv<<<512, 256, 0, stream>>>(enc, Wcomb, Wih, Whh, Wout, ws);
    prep_emb2<<<64, 512, 0, stream>>>(Wemb, Wcomb, ws);

    bahdanau_decoder<<<dim3(Bn), dim3(1024), (size_t)(Sn*Hn*2), stream>>>(
        bcomb, bih, bhh, bout, wvat, bvat, tgt, out, ws);
}

// Round 10
// 1402.961 us; speedup vs baseline: 1.6391x; 1.5578x over previous
//
#include <hip/hip_runtime.h>
#include <hip/hip_fp16.h>

#define Sn 128
#define Bn 64
#define Hn 512
#define Vn 100
#define TSn 31   // T-1 steps

typedef unsigned int   u32;
typedef unsigned short u16;
typedef _Float16 f16x2 __attribute__((ext_vector_type(2)));
typedef _Float16 f16x8 __attribute__((ext_vector_type(8)));
typedef float    f32x4 __attribute__((ext_vector_type(4)));

// ---- ws byte offsets (~12.4 MB) ----
#define OFF_ENC2  0ull           // fp16 [64][128][512]  8,388,608  (enc transposed [B][S][H])
#define OFF_WC2M  8388608ull     // MFMA-packed ctx-half Wcomb: 512 tiles x 1KB = 524,288
#define OFF_WIHM  8912896ull     // MFMA-packed Wih: 1536 tiles = 1,572,864
#define OFF_WHHM  10485760ull    // MFMA-packed Whh: 1536 tiles = 1,572,864
#define OFF_WOUTM 12058624ull    // MFMA-packed Wout (v padded to 112): 112 tiles = 114,688
#define OFF_EMB2  12173312ull    // f32 [100][512] = 204,800  (Wcomb_emb @ Wemb^T)

#define NT_IH 1536
#define NT_HH 1536
#define NT_C2 512
#define NT_OUT 112

__device__ __forceinline__ u16 f2h(float f){ _Float16 h=(_Float16)f; return __builtin_bit_cast(u16,h); }
__device__ __forceinline__ f16x2 uh2(u32 u){ return __builtin_bit_cast(f16x2,u); }
__device__ __forceinline__ float2 h2f(u32 u){ f16x2 h=uh2(u); return make_float2((float)h.x,(float)h.y); }
__device__ __forceinline__ u32 pack2h(float a, float b){ return (u32)f2h(a) | ((u32)f2h(b) << 16); }

__device__ __forceinline__ float fast_tanh(float x){
    float e = __expf(2.0f*x);
    return 1.0f - 2.0f/(e + 1.0f);
}
__device__ __forceinline__ float fast_sigmoid(float x){ return 1.0f/(1.0f + __expf(-x)); }

__device__ __forceinline__ float wave_sum(float v){
#pragma unroll
    for (int o = 32; o; o >>= 1) v += __shfl_xor(v, o);
    return v;
}
__device__ __forceinline__ float wave_max(float v){
#pragma unroll
    for (int o = 32; o; o >>= 1) v = fmaxf(v, __shfl_xor(v, o));
    return v;
}

__device__ __forceinline__ f32x4 mfma16(f16x8 a, f16x8 b, f32x4 c){
    return __builtin_amdgcn_mfma_f32_16x16x32_f16(a, b, c, 0, 0, 0);
}
// B fragment from packed tiles: tile = linear tile index, 64 uint4 per tile
__device__ __forceinline__ f16x8 ldB(const uint4* base, int tile, int lane){
    return __builtin_bit_cast(f16x8, base[(size_t)tile*64 + lane]);
}
// A fragment (broadcast vector v of 512 fp16 stored as u32 pairs in LDS):
// lane needs elems k = kf*32 + (lane>>4)*8 .. +8  -> uint4 index kf*4 + (lane>>4)
__device__ __forceinline__ f16x8 ldA(const u32* v32, int kf, int lane){
    return __builtin_bit_cast(f16x8, ((const uint4*)v32)[kf*4 + (lane>>4)]);
}

// ---------------- prep 1: enc transpose -> fp16 [B][S][H] ----------------
__global__ __launch_bounds__(256) void prep_enc(
    const float* __restrict__ enc, char* __restrict__ ws)
{
    const int t0 = blockIdx.x*256 + threadIdx.x;
    const int stride = gridDim.x*256;
    u16* de = (u16*)(ws + OFF_ENC2);
    for (int c = t0; c < Sn*Bn*Hn/4; c += stride) {
        const int h4 = c & 127;
        const int s  = (c >> 7) & 127;
        const int bb = c >> 14;
        float4 v = ((const float4*)enc)[(s*Bn + bb)*(Hn/4) + h4];
        ushort4 o;
        o.x = f2h(v.x); o.y = f2h(v.y); o.z = f2h(v.z); o.w = f2h(v.w);
        ((ushort4*)de)[c] = o;
    }
}

// ---------------- prep 2: pack weights into MFMA B-fragment tiles ----------------
// tile = 16x16x32 B block: for lane l, elem e: row(k) = kf*32 + (l>>4)*8 + e,
// col(j/n) = tile_j*16 + (l&15). Stored as 64 uint4 per tile (coalesced 1KB).
__global__ __launch_bounds__(256) void prep_pack(
    const float* __restrict__ Wih, const float* __restrict__ Whh,
    const float* __restrict__ Wcomb, const float* __restrict__ Wout,
    char* __restrict__ ws)
{
    const int total = (NT_IH + NT_HH + NT_C2 + NT_OUT)*64;
    for (int id = blockIdx.x*256 + threadIdx.x; id < total; id += gridDim.x*256) {
        const int l = id & 63;
        const int tile = id >> 6;
        const int kofs = ((l >> 4)*8);
        const float* s = nullptr;
        uint4* dst = nullptr;
        if (tile < NT_IH) {
            const int g = tile >> 9, jt = (tile >> 4) & 31, kf = tile & 15;
            s = Wih + ((size_t)(g*Hn + jt*16 + (l & 15)))*Hn + kf*32 + kofs;
            dst = (uint4*)(ws + OFF_WIHM) + (size_t)tile*64 + l;
        } else if (tile < NT_IH + NT_HH) {
            const int tt = tile - NT_IH;
            const int g = tt >> 9, jt = (tt >> 4) & 31, kf = tt & 15;
            s = Whh + ((size_t)(g*Hn + jt*16 + (l & 15)))*Hn + kf*32 + kofs;
            dst = (uint4*)(ws + OFF_WHHM) + (size_t)tt*64 + l;
        } else if (tile < NT_IH + NT_HH + NT_C2) {
            const int tt = tile - NT_IH - NT_HH;
            const int jt = tt >> 4, kf = tt & 15;
            s = Wcomb + ((size_t)(jt*16 + (l & 15)))*(2*Hn) + Hn + kf*32 + kofs;
            dst = (uint4*)(ws + OFF_WC2M) + (size_t)tt*64 + l;
        } else {
            const int tt = tile - NT_IH - NT_HH - NT_C2;
            const int jt = tt >> 4, kf = tt & 15;
            const int v = jt*16 + (l & 15);
            dst = (uint4*)(ws + OFF_WOUTM) + (size_t)tt*64 + l;
            if (v < Vn) s = Wout + (size_t)v*Hn + kf*32 + kofs;
        }
        uint4 val = {0u,0u,0u,0u};
        if (s) {
            const float4 a = *(const float4*)s;
            const float4 c = *(const float4*)(s + 4);
            val.x = pack2h(a.x, a.y); val.y = pack2h(a.z, a.w);
            val.z = pack2h(c.x, c.y); val.w = pack2h(c.z, c.w);
        }
        *dst = val;
    }
}

// ---------------- prep 3: EMB2[v][j] = sum_k Wcomb[j][k] * Wemb[v][k]  (validated r7-r9) ----------------
__global__ __launch_bounds__(512) void prep_emb2(
    const float* __restrict__ Wemb, const float* __restrict__ Wcomb,
    char* __restrict__ ws)
{
    float* EMB2 = (float*)(ws + OFF_EMB2);
    const int w = threadIdx.x >> 6;
    const int lane = threadIdx.x & 63;
    const int j = blockIdx.x*8 + w;
    const float4* wc = (const float4*)(Wcomb + (size_t)j*2*Hn);
#pragma unroll
    for (int pass = 0; pass < 2; ++pass) {
        const int v = lane + 64*pass;
        if (v < Vn) {
            const float4* we = (const float4*)(Wemb + (size_t)v*Hn);
            float acc = 0.0f;
            for (int k4 = 0; k4 < 128; ++k4) {
                const float4 a = wc[k4], b = we[k4];
                acc += a.x*b.x + a.y*b.y + a.z*b.z + a.w*b.w;
            }
            EMB2[(size_t)v*Hn + j] = acc;
        }
    }
}

// ---------------- main: 64 blocks x 1024 thr; ONE block per b; ZERO inter-block sync ----------------
__global__ __launch_bounds__(1024) void bahdanau_decoder(
    const float* __restrict__ bcomb, const float* __restrict__ bih,
    const float* __restrict__ bhh, const float* __restrict__ bout,
    const float* __restrict__ wvat, const float* __restrict__ bvat,
    const int* __restrict__ tgt, float* __restrict__ out, const char* __restrict__ ws)
{
    const uint4* WC2M  = (const uint4*)(ws + OFF_WC2M);
    const uint4* WIHM  = (const uint4*)(ws + OFF_WIHM);
    const uint4* WHHM  = (const uint4*)(ws + OFF_WHHM);
    const uint4* WOUTM = (const uint4*)(ws + OFF_WOUTM);
    const float* EMB2  = (const float*)(ws + OFF_EMB2);

    extern __shared__ __align__(16) u16 enc_lds[];   // [128][512] fp16 = 131072 B
    __shared__ __align__(16) float h_full[Hn];       // fp32 master h
    __shared__ __align__(16) u32   hh32[Hn/2];       // fp16-pair h_t
    __shared__ __align__(16) u32   ctx32[Hn/2];      // fp16-pair ctx
    __shared__ __align__(16) u16   x16[Hn];          // fp16 x
    __shared__ __align__(16) u16   hn16[Hn];         // fp16 h_{t+1}
    __shared__ __align__(16) float scores_s[Sn];
    __shared__ __align__(16) float attnw_s[Sn];
    __shared__ __align__(16) float2 pctx_s[4][256];
    __shared__ __align__(16) float llog[128];

    const int tid  = threadIdx.x;
    const int lane = tid & 63;
    const int wid  = tid >> 6;              // 0..15
    const int b    = blockIdx.x;

    // enc slice -> LDS (read once, resident all steps)
    {
        const uint4* src = (const uint4*)(ws + OFF_ENC2 + (size_t)b*Sn*Hn*2);
        for (int i = tid; i < Sn*Hn/8; i += 1024) ((uint4*)enc_lds)[i] = src[i];
    }
    if (tid < Hn)   h_full[tid] = 0.0f;
    if (tid < Hn/2) hh32[tid] = 0u;
    const float4 Wa = ((const float4*)wvat)[2*lane];
    const float4 Wb = ((const float4*)wvat)[2*lane+1];
    const float bv = bvat[0];
    __syncthreads();

    for (int t = 0; t < TSn; ++t) {
        // ---- P1: scores (wave per s-row; r4-proven) ----
        {
            const float4 Ha = ((const float4*)h_full)[2*lane];
            const float4 Hb = ((const float4*)h_full)[2*lane+1];
            for (int s = wid; s < Sn; s += 16) {
                const uint4 E = ((const uint4*)(enc_lds + s*Hn))[lane];
                const float2 e0 = h2f(E.x), e1 = h2f(E.y), e2 = h2f(E.z), e3 = h2f(E.w);
                float acc = fast_tanh(e0.x+Ha.x)*Wa.x + fast_tanh(e0.y+Ha.y)*Wa.y
                          + fast_tanh(e1.x+Ha.z)*Wa.z + fast_tanh(e1.y+Ha.w)*Wa.w
                          + fast_tanh(e2.x+Hb.x)*Wb.x + fast_tanh(e2.y+Hb.y)*Wb.y
                          + fast_tanh(e3.x+Hb.z)*Wb.z + fast_tanh(e3.y+Hb.w)*Wb.w;
                acc = wave_sum(acc);
                if (lane == 0) scores_s[s] = acc + bv;
            }
        }
        __syncthreads();

        // ---- P2: softmax over 128 (wave 0) ----
        if (wid == 0) {
            const float s0 = scores_s[lane], s1 = scores_s[lane+64];
            const float mx = wave_max(fmaxf(s0, s1));
            const float e0 = __expf(s0-mx), e1 = __expf(s1-mx);
            const float inv = 1.0f / wave_sum(e0 + e1);
            attnw_s[lane]    = e0 * inv;
            attnw_s[lane+64] = e1 * inv;
        }
        __syncthreads();

        // ---- P3: ctx partials (thread = (o-pair, s-chunk); r4-proven) ----
        {
            const int op = tid & 255, sc = tid >> 8;
            float ax = 0.0f, ay = 0.0f;
#pragma unroll 8
            for (int i2 = 0; i2 < 32; ++i2) {
                const int s = sc*32 + i2;
                const float a = attnw_s[s];
                const float2 ef = h2f(((const u32*)(enc_lds + s*Hn))[op]);
                ax += a*ef.x; ay += a*ef.y;
            }
            pctx_s[sc][op] = make_float2(ax, ay);
        }
        __syncthreads();
        if (tid < 256) {
            const float2 c0 = pctx_s[0][tid], c1 = pctx_s[1][tid];
            const float2 c2 = pctx_s[2][tid], c3 = pctx_s[3][tid];
            ctx32[tid] = pack2h(c0.x+c1.x+c2.x+c3.x, c0.y+c1.y+c2.y+c3.y);
        }
        __syncthreads();

        // ---- P4: x via MFMA (wave -> j-tiles {wid, wid+16}) ----
        {
            const int sym = tgt[t*Bn + b];
#pragma unroll
            for (int rep = 0; rep < 2; ++rep) {
                const int jt = wid + rep*16;
                f32x4 acc = {0.f,0.f,0.f,0.f};
#pragma unroll 4
                for (int kf = 0; kf < 16; ++kf)
                    acc = mfma16(ldA(ctx32, kf, lane), ldB(WC2M, jt*16 + kf, lane), acc);
                if (lane < 16) {
                    const int j = jt*16 + lane;
                    const float xv = acc[0] + EMB2[(size_t)sym*Hn + j] + bcomb[j];
                    x16[j] = f2h(fmaxf(xv, 0.0f));
                }
            }
        }
        __syncthreads();

        // ---- P5: GRU via MFMA (wave -> j-tiles {wid, wid+16}; 6 fused GEMV-tiles) ----
#pragma unroll
        for (int rep = 0; rep < 2; ++rep) {
            const int jt = wid + rep*16;
            f32x4 aR = {0.f,0.f,0.f,0.f}, aZ = {0.f,0.f,0.f,0.f};
            f32x4 aNi = {0.f,0.f,0.f,0.f}, aNh = {0.f,0.f,0.f,0.f};
#pragma unroll 4
            for (int kf = 0; kf < 16; ++kf) {
                const f16x8 ax = ldA((const u32*)x16, kf, lane);
                const f16x8 ah = ldA(hh32, kf, lane);
                aR  = mfma16(ax, ldB(WIHM, (0*32 + jt)*16 + kf, lane), aR);
                aR  = mfma16(ah, ldB(WHHM, (0*32 + jt)*16 + kf, lane), aR);
                aZ  = mfma16(ax, ldB(WIHM, (1*32 + jt)*16 + kf, lane), aZ);
                aZ  = mfma16(ah, ldB(WHHM, (1*32 + jt)*16 + kf, lane), aZ);
                aNi = mfma16(ax, ldB(WIHM, (2*32 + jt)*16 + kf, lane), aNi);
                aNh = mfma16(ah, ldB(WHHM, (2*32 + jt)*16 + kf, lane), aNh);
            }
            if (lane < 16) {
                const int j = jt*16 + lane;
                const float r = fast_sigmoid(aR[0] + bih[j] + bhh[j]);
                const float z = fast_sigmoid(aZ[0] + bih[Hn+j] + bhh[Hn+j]);
                const float n = fast_tanh(aNi[0] + bih[2*Hn+j] + r*(aNh[0] + bhh[2*Hn+j]));
                const float hv = (1.0f - z)*n + z*h_full[j];
                h_full[j] = hv;
                hn16[j] = f2h(hv);
            }
        }
        __syncthreads();

        // ---- P6: logits via MFMA (waves 0-6) || hh32 repack (waves 8-11) ----
        if (wid < 7) {
            f32x4 acc = {0.f,0.f,0.f,0.f};
#pragma unroll 4
            for (int kf = 0; kf < 16; ++kf)
                acc = mfma16(ldA((const u32*)hn16, kf, lane), ldB(WOUTM, wid*16 + kf, lane), acc);
            if (lane < 16) {
                const int v = wid*16 + lane;
                if (v < Vn) llog[v] = acc[0] + bout[v];
            }
        } else if (tid >= 512 && tid < 768) {
            const int i = tid - 512;
            hh32[i] = (u32)hn16[2*i] | ((u32)hn16[2*i+1] << 16);
        }
        __syncthreads();

        // ---- P7: log-softmax + store (wave 0) ----
        if (wid == 0) {
            const float l0 = llog[lane];
            const float l1 = (lane < 36) ? llog[64+lane] : -3.0e38f;
            const float mx = wave_max(fmaxf(l0, l1));
            const float e0 = __expf(l0 - mx);
            const float e1 = (lane < 36) ? __expf(l1 - mx) : 0.0f;
            const float lse = mx + __logf(wave_sum(e0 + e1));
            float* op = out + ((size_t)b*TSn + t)*Vn;
            op[lane] = l0 - lse;
            if (lane < 36) op[64 + lane] = l1 - lse;
        }
        __syncthreads();
    }
}

extern "C" void kernel_launch(void* const* d_in, const int* in_sizes, int n_in,
                              void* d_out, int out_size, void* d_ws, size_t ws_size,
                              hipStream_t stream) {
    const float* enc   = (const float*)d_in[0];
    const float* Wemb  = (const float*)d_in[1];
    const float* Wcomb = (const float*)d_in[2];
    const float* bcomb = (const float*)d_in[3];
    const float* Wih   = (const float*)d_in[4];
    const float* Whh   = (const float*)d_in[5];
    const float* bih   = (const float*)d_in[6];
    const float* bhh   = (const float*)d_in[7];
    const float* Wout  = (const float*)d_in[8];
    const float* bout  = (const float*)d_in[9];
    const float* wvat  = (const float*)d_in[10];
    const float* bvat  = (const float*)d_in[11];
    const int*   tgt   = (const int*)d_in[12];
    float* out = (float*)d_out;
    char*  ws  = (char*)d_ws;

    prep_enc<<<512, 256, 0, stream>>>(enc, ws);
    prep_pack<<<512, 256, 0, stream>>>(Wih, Whh, Wcomb, Wout, ws);
    prep_emb2<<<64, 512, 0, stream>>>(Wemb, Wcomb, ws);

    bahdanau_decoder<<<dim3(Bn), dim3(1024), (size_t)(Sn*Hn*2), stream>>>(
        bcomb, bih, bhh, bout, wvat, bvat, tgt, out, ws);
}

// Round 11
// 1324.182 us; speedup vs baseline: 1.7366x; 1.0595x over previous
//
#include <hip/hip_runtime.h>
#include <hip/hip_fp16.h>

#define Sn 128
#define Bn 64
#define Hn 512
#define Vn 100
#define TSn 31   // T-1 steps

typedef unsigned int   u32;
typedef unsigned short u16;
typedef _Float16 f16x2 __attribute__((ext_vector_type(2)));
typedef _Float16 f16x8 __attribute__((ext_vector_type(8)));
typedef float    f32x4 __attribute__((ext_vector_type(4)));

// ---- ws byte offsets (~12.4 MB) ----
#define OFF_ENC2  0ull           // fp16 [64][128][512]  8,388,608  (enc transposed [B][S][H])
#define OFF_WC2M  8388608ull     // MFMA-packed ctx-half Wcomb: 512 tiles x 1KB = 524,288
#define OFF_WIHM  8912896ull     // MFMA-packed Wih: 1536 tiles = 1,572,864
#define OFF_WHHM  10485760ull    // MFMA-packed Whh: 1536 tiles = 1,572,864
#define OFF_WOUTM 12058624ull    // MFMA-packed Wout (v padded to 112): 112 tiles = 114,688
#define OFF_EMB2  12173312ull    // f32 [100][512] = 204,800  (Wcomb_emb @ Wemb^T + bcomb)
#define OFF_GB    12378112ull    // f32 [4][512] = 8,192      (folded gate biases)

#define NT_IH 1536
#define NT_HH 1536
#define NT_C2 512
#define NT_OUT 112

__device__ __forceinline__ u16 f2h(float f){ _Float16 h=(_Float16)f; return __builtin_bit_cast(u16,h); }
__device__ __forceinline__ f16x2 uh2(u32 u){ return __builtin_bit_cast(f16x2,u); }
__device__ __forceinline__ float2 h2f(u32 u){ f16x2 h=uh2(u); return make_float2((float)h.x,(float)h.y); }
__device__ __forceinline__ u32 pack2h(float a, float b){ return (u32)f2h(a) | ((u32)f2h(b) << 16); }

__device__ __forceinline__ float fast_tanh(float x){
    float e = __expf(2.0f*x);
    return 1.0f - 2.0f/(e + 1.0f);
}
__device__ __forceinline__ float fast_sigmoid(float x){ return 1.0f/(1.0f + __expf(-x)); }

__device__ __forceinline__ float wave_sum(float v){
#pragma unroll
    for (int o = 32; o; o >>= 1) v += __shfl_xor(v, o);
    return v;
}
__device__ __forceinline__ float wave_max(float v){
#pragma unroll
    for (int o = 32; o; o >>= 1) v = fmaxf(v, __shfl_xor(v, o));
    return v;
}

__device__ __forceinline__ f32x4 mfma16(f16x8 a, f16x8 b, f32x4 c){
    return __builtin_amdgcn_mfma_f32_16x16x32_f16(a, b, c, 0, 0, 0);
}
__device__ __forceinline__ f16x8 ldB(const uint4* base, int tile, int lane){
    return __builtin_bit_cast(f16x8, base[(size_t)tile*64 + lane]);
}
// A fragment from a broadcast 512-fp16 vector in LDS (u16 array reinterpreted as u32 pairs)
__device__ __forceinline__ f16x8 ldA(const u32* v32, int kf, int lane){
    return __builtin_bit_cast(f16x8, ((const uint4*)v32)[kf*4 + (lane>>4)]);
}

// ---------------- prep 1: enc transpose -> fp16 [B][S][H]; folded gate biases ----------------
__global__ __launch_bounds__(256) void prep_enc(
    const float* __restrict__ enc, const float* __restrict__ bih,
    const float* __restrict__ bhh, char* __restrict__ ws)
{
    const int t0 = blockIdx.x*256 + threadIdx.x;
    const int stride = gridDim.x*256;
    u16* de = (u16*)(ws + OFF_ENC2);
    for (int c = t0; c < Sn*Bn*Hn/4; c += stride) {
        const int h4 = c & 127;
        const int s  = (c >> 7) & 127;
        const int bb = c >> 14;
        float4 v = ((const float4*)enc)[(s*Bn + bb)*(Hn/4) + h4];
        ushort4 o;
        o.x = f2h(v.x); o.y = f2h(v.y); o.z = f2h(v.z); o.w = f2h(v.w);
        ((ushort4*)de)[c] = o;
    }
    float* GB = (float*)(ws + OFF_GB);
    for (int j = t0; j < Hn; j += stride) {
        GB[j]        = bih[j]        + bhh[j];
        GB[Hn + j]   = bih[Hn + j]   + bhh[Hn + j];
        GB[2*Hn + j] = bih[2*Hn + j];
        GB[3*Hn + j] = bhh[2*Hn + j];
    }
}

// ---------------- prep 2: pack weights into MFMA B-fragment tiles (r10-validated) ----------------
__global__ __launch_bounds__(256) void prep_pack(
    const float* __restrict__ Wih, const float* __restrict__ Whh,
    const float* __restrict__ Wcomb, const float* __restrict__ Wout,
    char* __restrict__ ws)
{
    const int total = (NT_IH + NT_HH + NT_C2 + NT_OUT)*64;
    for (int id = blockIdx.x*256 + threadIdx.x; id < total; id += gridDim.x*256) {
        const int l = id & 63;
        const int tile = id >> 6;
        const int kofs = ((l >> 4)*8);
        const float* s = nullptr;
        uint4* dst = nullptr;
        if (tile < NT_IH) {
            const int g = tile >> 9, jt = (tile >> 4) & 31, kf = tile & 15;
            s = Wih + ((size_t)(g*Hn + jt*16 + (l & 15)))*Hn + kf*32 + kofs;
            dst = (uint4*)(ws + OFF_WIHM) + (size_t)tile*64 + l;
        } else if (tile < NT_IH + NT_HH) {
            const int tt = tile - NT_IH;
            const int g = tt >> 9, jt = (tt >> 4) & 31, kf = tt & 15;
            s = Whh + ((size_t)(g*Hn + jt*16 + (l & 15)))*Hn + kf*32 + kofs;
            dst = (uint4*)(ws + OFF_WHHM) + (size_t)tt*64 + l;
        } else if (tile < NT_IH + NT_HH + NT_C2) {
            const int tt = tile - NT_IH - NT_HH;
            const int jt = tt >> 4, kf = tt & 15;
            s = Wcomb + ((size_t)(jt*16 + (l & 15)))*(2*Hn) + Hn + kf*32 + kofs;
            dst = (uint4*)(ws + OFF_WC2M) + (size_t)tt*64 + l;
        } else {
            const int tt = tile - NT_IH - NT_HH - NT_C2;
            const int jt = tt >> 4, kf = tt & 15;
            const int v = jt*16 + (l & 15);
            dst = (uint4*)(ws + OFF_WOUTM) + (size_t)tt*64 + l;
            if (v < Vn) s = Wout + (size_t)v*Hn + kf*32 + kofs;
        }
        uint4 val = {0u,0u,0u,0u};
        if (s) {
            const float4 a = *(const float4*)s;
            const float4 c = *(const float4*)(s + 4);
            val.x = pack2h(a.x, a.y); val.y = pack2h(a.z, a.w);
            val.z = pack2h(c.x, c.y); val.w = pack2h(c.z, c.w);
        }
        *dst = val;
    }
}

// ---------------- prep 3: EMB2[v][j] = Wcomb_emb[j,:]·Wemb[v,:] + bcomb[j] ----------------
__global__ __launch_bounds__(512) void prep_emb2(
    const float* __restrict__ Wemb, const float* __restrict__ Wcomb,
    const float* __restrict__ bcomb, char* __restrict__ ws)
{
    float* EMB2 = (float*)(ws + OFF_EMB2);
    const int w = threadIdx.x >> 6;
    const int lane = threadIdx.x & 63;
    const int j = blockIdx.x*8 + w;
    const float4* wc = (const float4*)(Wcomb + (size_t)j*2*Hn);
    const float bc = bcomb[j];
#pragma unroll
    for (int pass = 0; pass < 2; ++pass) {
        const int v = lane + 64*pass;
        if (v < Vn) {
            const float4* we = (const float4*)(Wemb + (size_t)v*Hn);
            float acc = 0.0f;
            for (int k4 = 0; k4 < 128; ++k4) {
                const float4 a = wc[k4], b = we[k4];
                acc += a.x*b.x + a.y*b.y + a.z*b.z + a.w*b.w;
            }
            EMB2[(size_t)v*Hn + j] = acc + bc;
        }
    }
}

// ---------------- main: 64 blocks x 1024 thr; one block per b; zero inter-block sync ----------------
// Per step: overlap region (field waves 0-3; gh stream waves 4-14; logits wave 15)
// then critical region (x -> gi+gates).
__global__ __launch_bounds__(1024) void bahdanau_decoder(
    const float* __restrict__ bout, const float* __restrict__ wvat,
    const float* __restrict__ bvat, const int* __restrict__ tgt,
    float* __restrict__ out, const char* __restrict__ ws)
{
    const uint4* WC2M  = (const uint4*)(ws + OFF_WC2M);
    const uint4* WIHM  = (const uint4*)(ws + OFF_WIHM);
    const uint4* WHHM  = (const uint4*)(ws + OFF_WHHM);
    const uint4* WOUTM = (const uint4*)(ws + OFF_WOUTM);
    const float* EMB2  = (const float*)(ws + OFF_EMB2);
    const float* GB    = (const float*)(ws + OFF_GB);

    extern __shared__ __align__(16) u16 enc_lds[];   // [128][512] fp16 = 131072 B
    __shared__ __align__(16) float h_full[Hn];       // fp32 master h
    __shared__ __align__(16) u16   hn16[Hn];         // fp16 h (bytes == packed A layout)
    __shared__ __align__(16) u16   x16[Hn];          // fp16 x
    __shared__ __align__(16) u32   ctx32[Hn/2];      // fp16-pair ctx
    __shared__ __align__(16) float scores_s[Sn];
    __shared__ __align__(16) float attnw_s[Sn];
    __shared__ __align__(16) float ghacc[3][Hn];     // gh partial results
    __shared__ __align__(16) float llog[128];

    const int tid  = threadIdx.x;
    const int lane = tid & 63;
    const int wid  = tid >> 6;              // 0..15
    const int b    = blockIdx.x;

    // enc slice -> LDS (read once, resident all steps)
    {
        const uint4* src = (const uint4*)(ws + OFF_ENC2 + (size_t)b*Sn*Hn*2);
        for (int i = tid; i < Sn*Hn/8; i += 1024) ((uint4*)enc_lds)[i] = src[i];
    }
    if (tid < Hn) { h_full[tid] = 0.0f; hn16[tid] = 0; }
    const float4 Wa = ((const float4*)wvat)[2*lane];
    const float4 Wb = ((const float4*)wvat)[2*lane+1];
    const float bv = bvat[0];
    __syncthreads();

    for (int t = 0; t < TSn; ++t) {
        // ============ overlap region: everything here depends only on h_t ============
        // seg1
        if (wid < 4) {
            // field: scores for 32 s-rows per wave
            const float4 Ha = ((const float4*)h_full)[2*lane];
            const float4 Hb = ((const float4*)h_full)[2*lane+1];
            for (int i = 0; i < 32; ++i) {
                const int s = wid + 4*i;
                const uint4 E = ((const uint4*)(enc_lds + s*Hn))[lane];
                const float2 e0 = h2f(E.x), e1 = h2f(E.y), e2 = h2f(E.z), e3 = h2f(E.w);
                float acc = fast_tanh(e0.x+Ha.x)*Wa.x + fast_tanh(e0.y+Ha.y)*Wa.y
                          + fast_tanh(e1.x+Ha.z)*Wa.z + fast_tanh(e1.y+Ha.w)*Wa.w
                          + fast_tanh(e2.x+Hb.x)*Wb.x + fast_tanh(e2.y+Hb.y)*Wb.y
                          + fast_tanh(e3.x+Hb.z)*Wb.z + fast_tanh(e3.y+Hb.w)*Wb.w;
                acc = wave_sum(acc);
                if (lane == 0) scores_s[s] = acc + bv;
            }
        } else if (wid < 15) {
            // gh chunk A: tiles i = 0..3
#pragma unroll
            for (int i = 0; i < 4; ++i) {
                const int tt = (wid - 4) + 11*i;
                if (tt < 96) {
                    f32x4 acc = {0.f,0.f,0.f,0.f};
#pragma unroll 4
                    for (int kf = 0; kf < 16; ++kf)
                        acc = mfma16(ldA((const u32*)hn16, kf, lane),
                                     ldB(WHHM, tt*16 + kf, lane), acc);
                    if (lane < 16) ghacc[tt >> 5][(tt & 31)*16 + lane] = acc[0];
                }
            }
        } else {
            // wave 15: logits(h_t) -> llog; then log-softmax + store out[t-1] (self-contained)
#pragma unroll
            for (int tt = 0; tt < 7; ++tt) {
                f32x4 acc = {0.f,0.f,0.f,0.f};
#pragma unroll 4
                for (int kf = 0; kf < 16; ++kf)
                    acc = mfma16(ldA((const u32*)hn16, kf, lane),
                                 ldB(WOUTM, tt*16 + kf, lane), acc);
                if (lane < 16) {
                    const int v = tt*16 + lane;
                    if (v < Vn) llog[v] = acc[0] + bout[v];
                }
            }
            if (t > 0) {
                const float l0 = llog[lane];
                const float l1 = (lane < 36) ? llog[64+lane] : -3.0e38f;
                const float mx = wave_max(fmaxf(l0, l1));
                const float e0 = __expf(l0 - mx);
                const float e1 = (lane < 36) ? __expf(l1 - mx) : 0.0f;
                const float lse = mx + __logf(wave_sum(e0 + e1));
                float* op = out + ((size_t)b*TSn + (t-1))*Vn;
                op[lane] = l0 - lse;
                if (lane < 36) op[64 + lane] = l1 - lse;
            }
        }
        __syncthreads();

        // seg2
        if (wid == 0) {
            const float s0 = scores_s[lane], s1 = scores_s[lane+64];
            const float mx = wave_max(fmaxf(s0, s1));
            const float e0 = __expf(s0-mx), e1 = __expf(s1-mx);
            const float inv = 1.0f / wave_sum(e0 + e1);
            attnw_s[lane]    = e0 * inv;
            attnw_s[lane+64] = e1 * inv;
        } else if (wid >= 4 && wid < 15) {
            // gh chunk B: tiles i = 4..6
#pragma unroll
            for (int i = 4; i < 7; ++i) {
                const int tt = (wid - 4) + 11*i;
                if (tt < 96) {
                    f32x4 acc = {0.f,0.f,0.f,0.f};
#pragma unroll 4
                    for (int kf = 0; kf < 16; ++kf)
                        acc = mfma16(ldA((const u32*)hn16, kf, lane),
                                     ldB(WHHM, tt*16 + kf, lane), acc);
                    if (lane < 16) ghacc[tt >> 5][(tt & 31)*16 + lane] = acc[0];
                }
            }
        }
        __syncthreads();

        // seg3
        if (wid < 4) {
            // ctx: 256 threads, one o-pair each, full 128-s loop (no partials)
            const int op = tid;
            float ax = 0.0f, ay = 0.0f;
#pragma unroll 8
            for (int s = 0; s < Sn; ++s) {
                const float a = attnw_s[s];
                const float2 ef = h2f(((const u32*)enc_lds)[s*256 + op]);
                ax += a*ef.x; ay += a*ef.y;
            }
            ctx32[op] = pack2h(ax, ay);
        } else if (wid < 15) {
            // gh chunk C: tiles i = 7..8
#pragma unroll
            for (int i = 7; i < 9; ++i) {
                const int tt = (wid - 4) + 11*i;
                if (tt < 96) {
                    f32x4 acc = {0.f,0.f,0.f,0.f};
#pragma unroll 4
                    for (int kf = 0; kf < 16; ++kf)
                        acc = mfma16(ldA((const u32*)hn16, kf, lane),
                                     ldB(WHHM, tt*16 + kf, lane), acc);
                    if (lane < 16) ghacc[tt >> 5][(tt & 31)*16 + lane] = acc[0];
                }
            }
        }
        __syncthreads();

        // ============ critical region ============
        // P4: x via MFMA (all 16 waves, 2 j-tiles each)
        {
            const int sym = tgt[t*Bn + b];
#pragma unroll
            for (int rep = 0; rep < 2; ++rep) {
                const int jt = wid + rep*16;
                f32x4 acc = {0.f,0.f,0.f,0.f};
#pragma unroll 4
                for (int kf = 0; kf < 16; ++kf)
                    acc = mfma16(ldA(ctx32, kf, lane), ldB(WC2M, jt*16 + kf, lane), acc);
                if (lane < 16) {
                    const int j = jt*16 + lane;
                    const float xv = acc[0] + EMB2[(size_t)sym*Hn + j];  // bcomb folded
                    x16[j] = f2h(fmaxf(xv, 0.0f));
                }
            }
        }
        __syncthreads();

        // P5: gi via MFMA + gate combine (wave -> j-tiles {wid, wid+16})
#pragma unroll
        for (int rep = 0; rep < 2; ++rep) {
            const int jt = wid + rep*16;
            f32x4 aR = {0.f,0.f,0.f,0.f}, aZ = {0.f,0.f,0.f,0.f}, aNi = {0.f,0.f,0.f,0.f};
#pragma unroll 4
            for (int kf = 0; kf < 16; ++kf) {
                const f16x8 ax = ldA((const u32*)x16, kf, lane);
                aR  = mfma16(ax, ldB(WIHM, (0*32 + jt)*16 + kf, lane), aR);
                aZ  = mfma16(ax, ldB(WIHM, (1*32 + jt)*16 + kf, lane), aZ);
                aNi = mfma16(ax, ldB(WIHM, (2*32 + jt)*16 + kf, lane), aNi);
            }
            if (lane < 16) {
                const int j = jt*16 + lane;
                const float r = fast_sigmoid(aR[0]  + ghacc[0][j] + GB[j]);
                const float z = fast_sigmoid(aZ[0]  + ghacc[1][j] + GB[Hn + j]);
                const float n = fast_tanh(aNi[0] + GB[2*Hn + j] + r*(ghacc[2][j] + GB[3*Hn + j]));
                const float hv = (1.0f - z)*n + z*h_full[j];
                h_full[j] = hv;
                hn16[j] = f2h(hv);
            }
        }
        __syncthreads();
    }

    // ---- tail: logits + log-softmax for t = TSn-1 from final h ----
    if (wid == 15) {
#pragma unroll
        for (int tt = 0; tt < 7; ++tt) {
            f32x4 acc = {0.f,0.f,0.f,0.f};
#pragma unroll 4
            for (int kf = 0; kf < 16; ++kf)
                acc = mfma16(ldA((const u32*)hn16, kf, lane),
                             ldB(WOUTM, tt*16 + kf, lane), acc);
            if (lane < 16) {
                const int v = tt*16 + lane;
                if (v < Vn) llog[v] = acc[0] + bout[v];
            }
        }
        const float l0 = llog[lane];
        const float l1 = (lane < 36) ? llog[64+lane] : -3.0e38f;
        const float mx = wave_max(fmaxf(l0, l1));
        const float e0 = __expf(l0 - mx);
        const float e1 = (lane < 36) ? __expf(l1 - mx) : 0.0f;
        const float lse = mx + __logf(wave_sum(e0 + e1));
        float* op = out + ((size_t)b*TSn + (TSn-1))*Vn;
        op[lane] = l0 - lse;
        if (lane < 36) op[64 + lane] = l1 - lse;
    }
}

extern "C" void kernel_launch(void* const* d_in, const int* in_sizes, int n_in,
                              void* d_out, int out_size, void* d_ws, size_t ws_size,
                              hipStream_t stream) {
    const float* enc   = (const float*)d_in[0];
    const float* Wemb  = (const float*)d_in[1];
    const float* Wcomb = (const float*)d_in[2];
    const float* bcomb = (const float*)d_in[3];
    const float* Wih   = (const float*)d_in[4];
    const float* Whh   = (const float*)d_in[5];
    const float* bih   = (const float*)d_in[6];
    const float* bhh   = (const float*)d_in[7];
    const float* Wout  = (const float*)d_in[8];
    const float* bout  = (const float*)d_in[9];
    const float* wvat  = (const float*)d_in[10];
    const float* bvat  = (const float*)d_in[11];
    const int*   tgt   = (const int*)d_in[12];
    float* out = (float*)d_out;
    char*  ws  = (char*)d_ws;

    prep_enc<<<512, 256, 0, stream>>>(enc, bih, bhh, ws);
    prep_pack<<<512, 256, 0, stream>>>(Wih, Whh, Wcomb, Wout, ws);
    prep_emb2<<<64, 512, 0, stream>>>(Wemb, Wcomb, bcomb, ws);

    bahdanau_decoder<<<dim3(Bn), dim3(1024), (size_t)(Sn*Hn*2), stream>>>(
        bout, wvat, bvat, tgt, out, ws);
}